// Round 4
// baseline (190.791 us; speedup 1.0000x reference)
//
#include <hip/hip_runtime.h>
#include <cstdint>
#include <cstddef>

// DotProductAttention: O = softmax_q(QK^T/8 + log(mask)) @ V
// P = mask * exp(QK^T/8); L[b,k] = sum_q P; O = P @ (diag(1/L) V).
// R6: MFMA-density fix. R5 post-mortem: per-step per-wave math (16 MFMA = 77cy)
// was too small vs per-step overhead (~650cy) -> MfmaUtil capped ~13%. R6
// doubles math per staged byte and per barrier:
//  - attn: 32 q per wave (2 B-frag sets, 2 acc halves), block = 128 q,
//    32 MFMA/step/wave on the same K/V staging. Grid b16 x kc4 x qt16.
//  - stats: 128 persistent k' per wave (ak[8][2]), 16 MFMA/step/wave with
//    only 2 ds_reads. Grid b16 x qc4 x kt16.
// Verified pieces kept from R2/R5: swapped QK^T orientation + float4 mask,
// XOR-swizzled gl_lds staging, Pt same-wave roundtrip, epilogues, vtrans.

#define LSEQ 2048
#define DHEAD 64

typedef __bf16 v8bf __attribute__((ext_vector_type(8)));
typedef __bf16 v4bf __attribute__((ext_vector_type(4)));
typedef float v4f __attribute__((ext_vector_type(4)));

#define MFMA16(a, b, c) __builtin_amdgcn_mfma_f32_16x16x32_bf16(a, b, c, 0, 0, 0)

__device__ __forceinline__ void gl_lds16(const void* g, void* l) {
  __builtin_amdgcn_global_load_lds(
      (__attribute__((address_space(1))) void*)g,
      (__attribute__((address_space(3))) void*)l, 16, 0, 0);
}

// ---- K0: cast Q (x0.125, exact) / K to bf16; zero out and Lsum --------------
__global__ __launch_bounds__(256) void cast_qk(const float* __restrict__ Q,
                                               const float* __restrict__ K,
                                               __bf16* __restrict__ Qb,
                                               __bf16* __restrict__ Kb,
                                               float* __restrict__ outz,
                                               float* __restrict__ Lz) {
  size_t j = (size_t)blockIdx.x * 256 + threadIdx.x;
  size_t i = j * 4;
  float4 q = *(const float4*)(Q + i);
  float4 k = *(const float4*)(K + i);
  v4bf qo = {(__bf16)(q.x * 0.125f), (__bf16)(q.y * 0.125f),
             (__bf16)(q.z * 0.125f), (__bf16)(q.w * 0.125f)};
  v4bf ko = {(__bf16)k.x, (__bf16)k.y, (__bf16)k.z, (__bf16)k.w};
  *(v4bf*)(Qb + i) = qo;
  *(v4bf*)(Kb + i) = ko;
  float4 z = {0.f, 0.f, 0.f, 0.f};
  *(float4*)(outz + i) = z;  // out = 16*2048*64 = 2M floats = 2048*256*4
  if (j < (size_t)16 * LSEQ) Lz[j] = 0.f;
}

// ---- K1: Lsum[b,k] += sum_q mask*exp(S), swapped orient, 128 k'/wave --------
// Grid: b(16) x qc(4) x kt(16); XCD = kt%8 -> 2MB mask col-slice per XCD L2.
// S[k'][q] = mfma(A=K, B=Q): row(quad*4+r)=k' (8 subs), col(n)=q. 16 MFMA +
// 2 ds_read per step per wave; K persistent in 64 VGPRs.
__global__ __launch_bounds__(256, 3) void stats_k(const __bf16* __restrict__ Qb,
                                                  const __bf16* __restrict__ Kb,
                                                  const float* __restrict__ mask,
                                                  float* __restrict__ Lsum) {
  const int bx = blockIdx.x;
  const int b = bx >> 6;
  const int qc = (bx >> 4) & 3;
  const int k0 = (bx & 15) * 128;
  const int tid = threadIdx.x;
  const int w = tid >> 6, lane = tid & 63;
  const int quad = lane >> 4, n = lane & 15;

  __shared__ __align__(16) __bf16 Qt[2][64 * 64];
  __shared__ float psum[4][128];

#define STAGE_Q(buf, q0s)                                                        \
  {                                                                              \
    _Pragma("unroll") for (int i = 0; i < 2; ++i) {                              \
      int s = (w * 2 + i) * 64 + lane;                                           \
      int row = s >> 3, gc = (s & 7) ^ (row & 7);                                \
      gl_lds16(Qb + ((size_t)b * LSEQ + (q0s) + row) * DHEAD + gc * 8,           \
               &Qt[buf][s * 8]);                                                 \
    }                                                                            \
  }

  // persistent A=K fragments: lane n -> K row k0+sub*16+n, d-chunk quad
  v8bf ak[8][2];
#pragma unroll
  for (int sub = 0; sub < 8; ++sub)
#pragma unroll
    for (int dh = 0; dh < 2; ++dh)
      ak[sub][dh] = *(const v8bf*)(Kb + ((size_t)b * LSEQ + k0 + sub * 16 + n) * DHEAD +
                                   dh * 32 + quad * 8);

  float csum[8][4];
#pragma unroll
  for (int sub = 0; sub < 8; ++sub)
#pragma unroll
    for (int r = 0; r < 4; ++r) csum[sub][r] = 0.f;

  const int qbeg = qc * 512;
  STAGE_Q(0, qbeg);
  __syncthreads();

  int cur = 0;
#pragma unroll 1
  for (int ks = 0; ks < 8; ++ks) {
    const int qs = qbeg + ks * 64;
    // mask for this step (issued before stage: compiler wait leaves stage in
    // flight; __syncthreads at step end drains everything anyway)
    v4f m4[8];
#pragma unroll
    for (int sub = 0; sub < 8; ++sub)
      m4[sub] = *(const v4f*)(mask + (size_t)(qs + w * 16 + n) * LSEQ + k0 + sub * 16 +
                              quad * 4);
    if (ks < 7) STAGE_Q(cur ^ 1, qs + 64);

    const int qr = w * 16 + n;
    v8bf bq[2];
#pragma unroll
    for (int dh = 0; dh < 2; ++dh)
      bq[dh] = *(const v8bf*)&Qt[cur][qr * 64 + ((dh * 4 + quad) ^ (qr & 7)) * 8];

#pragma unroll
    for (int sub = 0; sub < 8; ++sub) {
      v4f c = {0.f, 0.f, 0.f, 0.f};
      c = MFMA16(ak[sub][0], bq[0], c);
      c = MFMA16(ak[sub][1], bq[1], c);
#pragma unroll
      for (int r = 0; r < 4; ++r) csum[sub][r] += m4[sub][r] * __expf(c[r]);
    }
    __syncthreads();  // drains stage vmcnt; publishes Qt[cur^1]
    cur ^= 1;
  }
#undef STAGE_Q

  // csum[sub][r]: partial colsum for k' = sub*16+quad*4+r. Reduce over n.
#pragma unroll
  for (int sub = 0; sub < 8; ++sub)
#pragma unroll
    for (int r = 0; r < 4; ++r) {
      float v = csum[sub][r];
      v += __shfl_xor(v, 1);
      v += __shfl_xor(v, 2);
      v += __shfl_xor(v, 4);
      v += __shfl_xor(v, 8);
      if (n == 0) psum[w][sub * 16 + quad * 4 + r] = v;
    }
  __syncthreads();
  if (tid < 128) {
    float s = psum[0][tid] + psum[1][tid] + psum[2][tid] + psum[3][tid];
    unsafeAtomicAdd(&Lsum[(size_t)b * LSEQ + k0 + tid], s);
  }
}

// ---- K2: Vts[b][v][k] = bf16(V[b][k][v] / L[b][k]) --------------------------
__global__ __launch_bounds__(256) void vtrans_k(const float* __restrict__ V,
                                                const float* __restrict__ Lsum,
                                                __bf16* __restrict__ Vts) {
  const int b = blockIdx.x >> 6;
  const int k0 = (blockIdx.x & 63) * 32;
  const int tid = threadIdx.x;
  __shared__ float tile[32][65];
  __shared__ float invl[32];
  if (tid < 32) invl[tid] = 1.0f / Lsum[(size_t)b * LSEQ + k0 + tid];
#pragma unroll
  for (int t = 0; t < 8; ++t) {
    int flat = t * 256 + tid;
    int k = flat >> 6, v = flat & 63;
    tile[k][v] = V[((size_t)b * LSEQ + k0 + k) * DHEAD + v];
  }
  __syncthreads();
#pragma unroll
  for (int t = 0; t < 8; ++t) {
    int flat = t * 256 + tid;
    int v = flat >> 5, k = flat & 31;
    Vts[((size_t)b * DHEAD + v) * LSEQ + k0 + k] = (__bf16)(tile[k][v] * invl[k]);
  }
}

// ---- K3: O += P @ Vts; 32 q per wave (128-q block), dbuf staging ------------
// Grid: b(16) x kc(4) x qt(16); XCD = qt%8 -> 2MB mask row-slice per XCD L2,
// and all kc partials of a q-tile on one XCD (out atomics stay in L2).
__global__ __launch_bounds__(256, 3) void attn_k(const __bf16* __restrict__ Qb,
                                                 const __bf16* __restrict__ Kb,
                                                 const __bf16* __restrict__ Vts,
                                                 const float* __restrict__ mask,
                                                 float* __restrict__ out) {
  const int bx = blockIdx.x;
  const int b = bx >> 6;
  const int kc = (bx >> 4) & 3;
  const int q0 = (bx & 15) * 128;
  const int tid = threadIdx.x;
  const int w = tid >> 6, lane = tid & 63;
  const int quad = lane >> 4, n = lane & 15;

  __shared__ __align__(16) __bf16 Kt[2][64 * 64];
  __shared__ __align__(16) __bf16 Vt[2][64 * 64];
  __shared__ __align__(16) __bf16 Pt[128][72];  // +8 pad rows, same-wave only

#define STAGE_KV(buf, kb2)                                                       \
  {                                                                              \
    _Pragma("unroll") for (int i = 0; i < 2; ++i) {                              \
      int s = (w * 2 + i) * 64 + lane;                                           \
      int row = s >> 3, gc = (s & 7) ^ (row & 7);                                \
      gl_lds16(Kb + ((size_t)b * LSEQ + (kb2) + row) * DHEAD + gc * 8,           \
               &Kt[buf][s * 8]);                                                 \
      gl_lds16(Vts + ((size_t)b * DHEAD + row) * LSEQ + (kb2) + gc * 8,          \
               &Vt[buf][s * 8]);                                                 \
    }                                                                            \
  }

  const int qg0 = q0 + w * 32 + n;  // q-half 0; half 1 = qg0 + 16

  // persistent B=Q fragments for both q-halves (Qb already scaled by 1/8)
  v8bf bq[2][2];
#pragma unroll
  for (int h = 0; h < 2; ++h)
#pragma unroll
    for (int dh = 0; dh < 2; ++dh)
      bq[h][dh] = *(const v8bf*)(Qb + ((size_t)b * LSEQ + qg0 + h * 16) * DHEAD +
                                 dh * 32 + quad * 8);

  v4f acc[2][4];
#pragma unroll
  for (int h = 0; h < 2; ++h)
#pragma unroll
    for (int vs = 0; vs < 4; ++vs) acc[h][vs] = (v4f){0.f, 0.f, 0.f, 0.f};

  const int kbeg = kc * 512;
  STAGE_KV(0, kbeg);
  __syncthreads();

  int cur = 0;
#pragma unroll 1
  for (int ks = 0; ks < 8; ++ks) {
    const int kb = kbeg + ks * 64;
    // mask for this step, both q-halves (L2-hot; issued before stage)
    v4f m4[2][4];
#pragma unroll
    for (int h = 0; h < 2; ++h)
#pragma unroll
      for (int sub = 0; sub < 4; ++sub)
        m4[h][sub] = *(const v4f*)(mask + (size_t)(qg0 + h * 16) * LSEQ + kb + sub * 16 +
                                   quad * 4);
    if (ks < 7) STAGE_KV(cur ^ 1, kb + 64);

    // QK^T swapped: S[k'][q] for both q-halves; P -> Pt (v4bf, own-wave rows)
#pragma unroll
    for (int sub = 0; sub < 4; ++sub) {
      const int kr = sub * 16 + n;
      v8bf a0 = *(const v8bf*)&Kt[cur][kr * 64 + ((quad) ^ (kr & 7)) * 8];
      v8bf a1 = *(const v8bf*)&Kt[cur][kr * 64 + ((4 + quad) ^ (kr & 7)) * 8];
#pragma unroll
      for (int h = 0; h < 2; ++h) {
        v4f c = {0.f, 0.f, 0.f, 0.f};
        c = MFMA16(a0, bq[h][0], c);
        c = MFMA16(a1, bq[h][1], c);
        v4bf pv;
#pragma unroll
        for (int r = 0; r < 4; ++r) pv[r] = (__bf16)(m4[h][sub][r] * __expf(c[r]));
        *(v4bf*)&Pt[w * 32 + h * 16 + n][sub * 16 + quad * 4] = pv;
      }
    }
    __asm__ volatile("s_waitcnt lgkmcnt(0)" ::: "memory");  // own-wave P visible

    // PV: A = P rows (own wave, both halves), B = Vt (shared across halves)
#pragma unroll
    for (int kk = 0; kk < 2; ++kk) {
      v8bf ap0 = *(const v8bf*)&Pt[w * 32 + n][kk * 32 + quad * 8];
      v8bf ap1 = *(const v8bf*)&Pt[w * 32 + 16 + n][kk * 32 + quad * 8];
#pragma unroll
      for (int vs = 0; vs < 4; ++vs) {
        const int vr = vs * 16 + n;
        v8bf bv = *(const v8bf*)&Vt[cur][vr * 64 + ((kk * 4 + quad) ^ (vr & 7)) * 8];
        acc[0][vs] = MFMA16(ap0, bv, acc[0][vs]);
        acc[1][vs] = MFMA16(ap1, bv, acc[1][vs]);
      }
    }
    __syncthreads();  // drains stage vmcnt; publishes next buffers
    cur ^= 1;
  }
#undef STAGE_KV

  // C[q][v]: row q = w*32 + h*16 + quad*4 + r, col v = vs*16 + n
#pragma unroll
  for (int h = 0; h < 2; ++h)
#pragma unroll
    for (int vs = 0; vs < 4; ++vs)
#pragma unroll
      for (int r = 0; r < 4; ++r)
        unsafeAtomicAdd(&out[((size_t)b * LSEQ + q0 + w * 32 + h * 16 + quad * 4 + r) *
                                 DHEAD +
                             vs * 16 + n],
                        acc[h][vs][r]);
}

extern "C" void kernel_launch(void* const* d_in, const int* in_sizes, int n_in,
                              void* d_out, int out_size, void* d_ws, size_t ws_size,
                              hipStream_t stream) {
  const float* Q = (const float*)d_in[0];
  const float* K = (const float*)d_in[1];
  const float* V = (const float*)d_in[2];
  const float* mask = (const float*)d_in[3];
  float* out = (float*)d_out;

  char* ws = (char*)d_ws;
  // ws: Qb 4MiB | Kb 4MiB | Vts 4MiB | Lsum 128KiB  (12.13 MiB)
  __bf16* Qb = (__bf16*)(ws);
  __bf16* Kb = (__bf16*)(ws + (4 << 20));
  __bf16* Vts = (__bf16*)(ws + (8 << 20));
  float* Lsum = (float*)(ws + (12 << 20));
  const size_t need = ((size_t)12 << 20) + (1 << 17);
  if (ws_size < need) return;  // workspace too small — fail loudly (poison out)

  cast_qk<<<2048, 256, 0, stream>>>(Q, K, Qb, Kb, out, Lsum);
  stats_k<<<1024, 256, 0, stream>>>(Qb, Kb, mask, Lsum);
  vtrans_k<<<1024, 256, 0, stream>>>(V, Lsum, Vts);
  attn_k<<<1024, 256, 0, stream>>>(Qb, Kb, Vts, mask, out);
}

// Round 5
// 184.286 us; speedup vs baseline: 1.0353x; 1.0353x over previous
//
#include <hip/hip_runtime.h>
#include <cstdint>
#include <cstddef>

// DotProductAttention: O = softmax_q(QK^T/8 + log(mask)) @ V
// P = mask * exp(QK^T/8); L[b,k] = sum_q P; O = P @ (diag(1/L) V).
// R7: occupancy + overlap. Evidence across R2..R6: kernels are latency-bound;
// resident-wave count is the controlling variable (R2 @6 blocks/CU = best).
//  - attn: split-phase single-buffer pipeline. QK reads only Kt, PV reads only
//    Vt -> stage Kt(t+1) after barrier1 (overlaps PV), stage Vt(t+1) after
//    barrier2 (overlaps next QK). LDS = Kt 8K + Vt 8K + Pt 16K = 32KB ->
//    5 blocks/CU (20 waves). 32 q/wave density kept from R6.
//  - Pt conflict fix: 16B-unit XOR swizzle (unit ^ (row&7)) on write+read
//    replaces the [72] pad (R5/R6 had 1.57M conflicts from the pad pattern).
//  - stats: 64 k'/wave (ak 32 VGPR, ~105 total -> 4 waves/SIMD), dbuf Qt,
//    1 barrier/step, lane-local csum + float4 mask (swapped orientation).
//  - s_setprio(1) around MFMA clusters (T5; phase-split structure present).

#define LSEQ 2048
#define DHEAD 64

typedef __bf16 v8bf __attribute__((ext_vector_type(8)));
typedef __bf16 v4bf __attribute__((ext_vector_type(4)));
typedef float v4f __attribute__((ext_vector_type(4)));

#define MFMA16(a, b, c) __builtin_amdgcn_mfma_f32_16x16x32_bf16(a, b, c, 0, 0, 0)

__device__ __forceinline__ void gl_lds16(const void* g, void* l) {
  __builtin_amdgcn_global_load_lds(
      (__attribute__((address_space(1))) void*)g,
      (__attribute__((address_space(3))) void*)l, 16, 0, 0);
}

// ---- K0: cast Q (x0.125, exact) / K to bf16; zero out and Lsum --------------
__global__ __launch_bounds__(256) void cast_qk(const float* __restrict__ Q,
                                               const float* __restrict__ K,
                                               __bf16* __restrict__ Qb,
                                               __bf16* __restrict__ Kb,
                                               float* __restrict__ outz,
                                               float* __restrict__ Lz) {
  size_t j = (size_t)blockIdx.x * 256 + threadIdx.x;
  size_t i = j * 4;
  float4 q = *(const float4*)(Q + i);
  float4 k = *(const float4*)(K + i);
  v4bf qo = {(__bf16)(q.x * 0.125f), (__bf16)(q.y * 0.125f),
             (__bf16)(q.z * 0.125f), (__bf16)(q.w * 0.125f)};
  v4bf ko = {(__bf16)k.x, (__bf16)k.y, (__bf16)k.z, (__bf16)k.w};
  *(v4bf*)(Qb + i) = qo;
  *(v4bf*)(Kb + i) = ko;
  float4 z = {0.f, 0.f, 0.f, 0.f};
  *(float4*)(outz + i) = z;  // out = 16*2048*64 = 2M floats = 2048*256*4
  if (j < (size_t)16 * LSEQ) Lz[j] = 0.f;
}

// ---- K1: Lsum[b,k] += sum_q mask*exp(S), swapped orient, 64 k'/wave ---------
// Grid: b(16) x qc(4) x kt(32); XCD = kt%8 -> 2MB mask col-slice per XCD L2.
// S[k'][q] = mfma(A=K, B=Q): row(quad*4+r)=k', col(n)=q. csum lane-local;
// mask float4 along q? no: along k is contiguous for a fixed q-row (mask is
// [q][k] row-major) -> here we need mask[qs+w*16+n][k0+sub*16+quad*4..+4]:
// contiguous in k ✓ (swapped C layout puts 4 consecutive k in c[0..3]).
__global__ __launch_bounds__(256, 4) void stats_k(const __bf16* __restrict__ Qb,
                                                  const __bf16* __restrict__ Kb,
                                                  const float* __restrict__ mask,
                                                  float* __restrict__ Lsum) {
  const int bx = blockIdx.x;
  const int b = bx >> 7;
  const int qc = (bx >> 5) & 3;
  const int k0 = (bx & 31) * 64;
  const int tid = threadIdx.x;
  const int w = tid >> 6, lane = tid & 63;
  const int quad = lane >> 4, n = lane & 15;

  __shared__ __align__(16) __bf16 Qt[2][64 * 64];
  __shared__ float psum[4][64];

#define STAGE_Q(buf, q0s)                                                        \
  {                                                                              \
    _Pragma("unroll") for (int i = 0; i < 2; ++i) {                              \
      int s = (w * 2 + i) * 64 + lane;                                           \
      int row = s >> 3, gc = (s & 7) ^ (row & 7);                                \
      gl_lds16(Qb + ((size_t)b * LSEQ + (q0s) + row) * DHEAD + gc * 8,           \
               &Qt[buf][s * 8]);                                                 \
    }                                                                            \
  }

  // persistent A=K fragments: lane n -> K row k0+sub*16+n, d-chunk quad
  v8bf ak[4][2];
#pragma unroll
  for (int sub = 0; sub < 4; ++sub)
#pragma unroll
    for (int dh = 0; dh < 2; ++dh)
      ak[sub][dh] = *(const v8bf*)(Kb + ((size_t)b * LSEQ + k0 + sub * 16 + n) * DHEAD +
                                   dh * 32 + quad * 8);

  float csum[4][4];
#pragma unroll
  for (int sub = 0; sub < 4; ++sub)
#pragma unroll
    for (int r = 0; r < 4; ++r) csum[sub][r] = 0.f;

  const int qbeg = qc * 512;
  STAGE_Q(0, qbeg);
  __syncthreads();

  int cur = 0;
#pragma unroll 1
  for (int ks = 0; ks < 8; ++ks) {
    const int qs = qbeg + ks * 64;
    // mask first (older vmcnt slots), stage after -> exp's vmcnt wait leaves
    // the stage in flight
    v4f m4[4];
#pragma unroll
    for (int sub = 0; sub < 4; ++sub)
      m4[sub] = *(const v4f*)(mask + (size_t)(qs + w * 16 + n) * LSEQ + k0 + sub * 16 +
                              quad * 4);
    if (ks < 7) STAGE_Q(cur ^ 1, qs + 64);

    const int qr = w * 16 + n;
    v8bf bq[2];
#pragma unroll
    for (int dh = 0; dh < 2; ++dh)
      bq[dh] = *(const v8bf*)&Qt[cur][qr * 64 + ((dh * 4 + quad) ^ (qr & 7)) * 8];

    __builtin_amdgcn_s_setprio(1);
#pragma unroll
    for (int sub = 0; sub < 4; ++sub) {
      v4f c = {0.f, 0.f, 0.f, 0.f};
      c = MFMA16(ak[sub][0], bq[0], c);
      c = MFMA16(ak[sub][1], bq[1], c);
#pragma unroll
      for (int r = 0; r < 4; ++r) csum[sub][r] += m4[sub][r] * __expf(c[r]);
    }
    __builtin_amdgcn_s_setprio(0);
    __syncthreads();  // drains stage vmcnt; publishes Qt[cur^1]
    cur ^= 1;
  }
#undef STAGE_Q

  // csum[sub][r]: partial colsum for k' = sub*16+quad*4+r. Reduce over n.
#pragma unroll
  for (int sub = 0; sub < 4; ++sub)
#pragma unroll
    for (int r = 0; r < 4; ++r) {
      float v = csum[sub][r];
      v += __shfl_xor(v, 1);
      v += __shfl_xor(v, 2);
      v += __shfl_xor(v, 4);
      v += __shfl_xor(v, 8);
      if (n == 0) psum[w][sub * 16 + quad * 4 + r] = v;
    }
  __syncthreads();
  if (tid < 64) {
    float s = psum[0][tid] + psum[1][tid] + psum[2][tid] + psum[3][tid];
    unsafeAtomicAdd(&Lsum[(size_t)b * LSEQ + k0 + tid], s);
  }
}

// ---- K2: Vts[b][v][k] = bf16(V[b][k][v] / L[b][k]) --------------------------
__global__ __launch_bounds__(256) void vtrans_k(const float* __restrict__ V,
                                                const float* __restrict__ Lsum,
                                                __bf16* __restrict__ Vts) {
  const int b = blockIdx.x >> 6;
  const int k0 = (blockIdx.x & 63) * 32;
  const int tid = threadIdx.x;
  __shared__ float tile[32][65];
  __shared__ float invl[32];
  if (tid < 32) invl[tid] = 1.0f / Lsum[(size_t)b * LSEQ + k0 + tid];
#pragma unroll
  for (int t = 0; t < 8; ++t) {
    int flat = t * 256 + tid;
    int k = flat >> 6, v = flat & 63;
    tile[k][v] = V[((size_t)b * LSEQ + k0 + k) * DHEAD + v];
  }
  __syncthreads();
#pragma unroll
  for (int t = 0; t < 8; ++t) {
    int flat = t * 256 + tid;
    int v = flat >> 5, k = flat & 31;
    Vts[((size_t)b * DHEAD + v) * LSEQ + k0 + k] = (__bf16)(tile[k][v] * invl[k]);
  }
}

// ---- K3: O += P @ Vts; split-phase single-buffer pipeline, 32 q/wave --------
// Grid: b(16) x kc(4) x qt(16); XCD = qt%8 -> mask row-slices and out-atomic
// partials per q-tile stay on one XCD's L2.
// Schedule: QK(reads Kt)+exp+Ptwrite | barrier1 | stageK(t+1) | PV(reads Vt,Pt)
// | barrier2 | stageV(t+1). Each stage overlaps a ~300cy compute phase.
__global__ __launch_bounds__(256, 4) void attn_k(const __bf16* __restrict__ Qb,
                                                 const __bf16* __restrict__ Kb,
                                                 const __bf16* __restrict__ Vts,
                                                 const float* __restrict__ mask,
                                                 float* __restrict__ out) {
  const int bx = blockIdx.x;
  const int b = bx >> 6;
  const int kc = (bx >> 4) & 3;
  const int q0 = (bx & 15) * 128;
  const int tid = threadIdx.x;
  const int w = tid >> 6, lane = tid & 63;
  const int quad = lane >> 4, n = lane & 15;

  __shared__ __align__(16) __bf16 Kt[64 * 64];
  __shared__ __align__(16) __bf16 Vt[64 * 64];
  __shared__ __align__(16) __bf16 Pt[128 * 64];  // 16B-unit XOR swizzled

#define STAGE_K(kb2)                                                             \
  {                                                                              \
    _Pragma("unroll") for (int i = 0; i < 2; ++i) {                              \
      int s = (w * 2 + i) * 64 + lane;                                           \
      int row = s >> 3, gc = (s & 7) ^ (row & 7);                                \
      gl_lds16(Kb + ((size_t)b * LSEQ + (kb2) + row) * DHEAD + gc * 8,           \
               &Kt[s * 8]);                                                      \
    }                                                                            \
  }
#define STAGE_V(kb2)                                                             \
  {                                                                              \
    _Pragma("unroll") for (int i = 0; i < 2; ++i) {                              \
      int s = (w * 2 + i) * 64 + lane;                                           \
      int row = s >> 3, gc = (s & 7) ^ (row & 7);                                \
      gl_lds16(Vts + ((size_t)b * DHEAD + row) * LSEQ + (kb2) + gc * 8,          \
               &Vt[s * 8]);                                                      \
    }                                                                            \
  }

  const int qg0 = q0 + w * 32 + n;  // q-half 0; half 1 = qg0 + 16

  // persistent B=Q fragments for both q-halves (Qb already scaled by 1/8)
  v8bf bq[2][2];
#pragma unroll
  for (int h = 0; h < 2; ++h)
#pragma unroll
    for (int dh = 0; dh < 2; ++dh)
      bq[h][dh] = *(const v8bf*)(Qb + ((size_t)b * LSEQ + qg0 + h * 16) * DHEAD +
                                 dh * 32 + quad * 8);

  v4f acc[2][4];
#pragma unroll
  for (int h = 0; h < 2; ++h)
#pragma unroll
    for (int vs = 0; vs < 4; ++vs) acc[h][vs] = (v4f){0.f, 0.f, 0.f, 0.f};

  const int kbeg = kc * 512;
  STAGE_K(kbeg);
  STAGE_V(kbeg);
  __syncthreads();

#pragma unroll 1
  for (int ks = 0; ks < 8; ++ks) {
    const int kb = kbeg + ks * 64;
    // mask for this step, both q-halves (contiguous 4 k per v4f)
    v4f m4[2][4];
#pragma unroll
    for (int h = 0; h < 2; ++h)
#pragma unroll
      for (int sub = 0; sub < 4; ++sub)
        m4[h][sub] = *(const v4f*)(mask + (size_t)(qg0 + h * 16) * LSEQ + kb + sub * 16 +
                                   quad * 4);

    // QK^T swapped: S[k'][q] both halves; P -> Pt (swizzled v4bf, own rows)
    __builtin_amdgcn_s_setprio(1);
#pragma unroll
    for (int sub = 0; sub < 4; ++sub) {
      const int kr = sub * 16 + n;
      v8bf a0 = *(const v8bf*)&Kt[kr * 64 + ((quad) ^ (kr & 7)) * 8];
      v8bf a1 = *(const v8bf*)&Kt[kr * 64 + ((4 + quad) ^ (kr & 7)) * 8];
#pragma unroll
      for (int h = 0; h < 2; ++h) {
        v4f c = {0.f, 0.f, 0.f, 0.f};
        c = MFMA16(a0, bq[h][0], c);
        c = MFMA16(a1, bq[h][1], c);
        v4bf pv;
#pragma unroll
        for (int r = 0; r < 4; ++r) pv[r] = (__bf16)(m4[h][sub][r] * __expf(c[r]));
        // write P[row=q][e=sub*16+quad*4..+4]; 16B-unit U=sub*2+(quad>>1),
        // swizzle U^=(row&7)=(n&7); 8B slot = quad&1
        const int prow = w * 32 + h * 16 + n;
        *(v4bf*)((char*)Pt + prow * 128 + (((sub * 2 + (quad >> 1)) ^ (n & 7)) << 4) +
                 ((quad & 1) << 3)) = pv;
      }
    }
    __builtin_amdgcn_s_setprio(0);
    __syncthreads();  // barrier1: Kt free (reads done); Pt published
    if (ks < 7) STAGE_K(kb + 64);  // overlaps PV below

    // PV: A = P rows (deswizzled b128), B = Vt
    __builtin_amdgcn_s_setprio(1);
#pragma unroll
    for (int kk = 0; kk < 2; ++kk) {
      const int pr0 = w * 32 + n, pr1 = pr0 + 16;
      v8bf ap0 =
          *(const v8bf*)((char*)Pt + pr0 * 128 + (((kk * 4 + quad) ^ (n & 7)) << 4));
      v8bf ap1 =
          *(const v8bf*)((char*)Pt + pr1 * 128 + (((kk * 4 + quad) ^ (n & 7)) << 4));
#pragma unroll
      for (int vs = 0; vs < 4; ++vs) {
        const int vr = vs * 16 + n;
        v8bf bv = *(const v8bf*)&Vt[vr * 64 + ((kk * 4 + quad) ^ (vr & 7)) * 8];
        acc[0][vs] = MFMA16(ap0, bv, acc[0][vs]);
        acc[1][vs] = MFMA16(ap1, bv, acc[1][vs]);
      }
    }
    __builtin_amdgcn_s_setprio(0);
    __syncthreads();  // barrier2: Vt free; Kt(ks+1) stage drained
    if (ks < 7) STAGE_V(kb + 64);  // overlaps next QK; drained at barrier1
  }
#undef STAGE_K
#undef STAGE_V

  // C[q][v]: row q = w*32 + h*16 + quad*4 + r, col v = vs*16 + n
#pragma unroll
  for (int h = 0; h < 2; ++h)
#pragma unroll
    for (int vs = 0; vs < 4; ++vs)
#pragma unroll
      for (int r = 0; r < 4; ++r)
        unsafeAtomicAdd(&out[((size_t)b * LSEQ + q0 + w * 32 + h * 16 + quad * 4 + r) *
                                 DHEAD +
                             vs * 16 + n],
                        acc[h][vs][r]);
}

extern "C" void kernel_launch(void* const* d_in, const int* in_sizes, int n_in,
                              void* d_out, int out_size, void* d_ws, size_t ws_size,
                              hipStream_t stream) {
  const float* Q = (const float*)d_in[0];
  const float* K = (const float*)d_in[1];
  const float* V = (const float*)d_in[2];
  const float* mask = (const float*)d_in[3];
  float* out = (float*)d_out;

  char* ws = (char*)d_ws;
  // ws: Qb 4MiB | Kb 4MiB | Vts 4MiB | Lsum 128KiB  (12.13 MiB)
  __bf16* Qb = (__bf16*)(ws);
  __bf16* Kb = (__bf16*)(ws + (4 << 20));
  __bf16* Vts = (__bf16*)(ws + (8 << 20));
  float* Lsum = (float*)(ws + (12 << 20));
  const size_t need = ((size_t)12 << 20) + (1 << 17);
  if (ws_size < need) return;  // workspace too small — fail loudly (poison out)

  cast_qk<<<2048, 256, 0, stream>>>(Q, K, Qb, Kb, out, Lsum);
  stats_k<<<2048, 256, 0, stream>>>(Qb, Kb, mask, Lsum);
  vtrans_k<<<1024, 256, 0, stream>>>(V, Lsum, Vts);
  attn_k<<<1024, 256, 0, stream>>>(Qb, Kb, Vts, mask, out);
}